// Round 14
// baseline (399.913 us; speedup 1.0000x reference)
//
#include <hip/hip_runtime.h>
#include <math.h>

#define KF 256      // input features
#define F1 128      // layer-1 hidden (8 heads x 16)
#define NH 8        // heads layer 1
#define NC 16       // channels per head layer 1
#define NCLS 40     // layer-2 output classes
#define NEG 0.2f    // leaky relu slope
#define BM 64       // gemm1 row tile

static __device__ __forceinline__ float lrelu(float v) { return fmaxf(v, NEG * v); }

// round-to-nearest-even bf16 packing helpers
static __device__ __forceinline__ unsigned bf16r(float a) {
    unsigned u = __float_as_uint(a);
    return (u + 0x7fffu + ((u >> 16) & 1u)) >> 16;
}
static __device__ __forceinline__ unsigned bf16pack2(float a, float b) {
    return bf16r(a) | (bf16r(b) << 16);
}
static __device__ __forceinline__ float2 bf2unpack(unsigned v) {
    float2 r;
    r.x = __uint_as_float(v << 16);
    r.y = __uint_as_float(v & 0xffff0000u);
    return r;
}

typedef __attribute__((ext_vector_type(8))) short bf16x8;
typedef __attribute__((ext_vector_type(4))) float f32x4;

// ---------------- W1 -> bf16 B-fragment-order buffer (one-time prep) ----------------
__global__ __launch_bounds__(256) void wprep_kernel(const float* __restrict__ W1,
                                                    unsigned short* __restrict__ wfrag)
{
    int gid = blockIdx.x * 256 + threadIdx.x;
    if (gid >= KF * F1) return;
    int k = gid >> 7, nn = gid & 127;
    int kt = k >> 6, ks = (k >> 5) & 1, oct = (k >> 3) & 3, e = k & 7;
    int nt = nn >> 4, ln = (nn & 15) + 16 * oct;
    int idx = (((kt * 8 + nt) * 2 + ks) * 64 + ln) * 8 + e;
    wfrag[idx] = (unsigned short)bf16r(W1[gid]);
}

// ---------------- GEMM1 (MFMA bf16) + fused attention logits (round-8 design) ----------------
// Outputs in HEAD-MAJOR layout: h1h[(h*n+row)*16+col], a_srcH/a_dstH[h*n+row].
__global__ __launch_bounds__(256) void gemm1_kernel(const float* __restrict__ x,
        const unsigned short* __restrict__ wfrag,
        const float* __restrict__ att_src, const float* __restrict__ att_dst,
        unsigned short* __restrict__ h1h, float* __restrict__ a_srcH, float* __restrict__ a_dstH,
        int n)
{
    __shared__ __align__(16) unsigned short Al[4096];  // A 64x64 frag-order, 8KB
    __shared__ __align__(16) unsigned short Bl[8192];  // B 64x128 frag-order, 16KB
    const int t = threadIdx.x;
    const int w = t >> 6, lane = t & 63;
    const int row0 = blockIdx.x * BM;

    f32x4 acc[8];
#pragma unroll
    for (int i = 0; i < 8; ++i) acc[i] = (f32x4){0.f, 0.f, 0.f, 0.f};

    for (int kt = 0; kt < 4; ++kt) {
        // stage A: x[row0..+64][kt*64..+64] -> bf16 fragment order
        {
            const int k4 = t & 15;
            const int ks = k4 >> 3;
            const int oct = (k4 >> 1) & 3;
            const int koff = (k4 & 1) * 4;
#pragma unroll
            for (int it = 0; it < 4; ++it) {
                int r = (t >> 4) + it * 16;
                int gr = row0 + r;
                float4 v = make_float4(0.f, 0.f, 0.f, 0.f);
                if (gr < n) v = *(const float4*)&x[(size_t)gr * KF + kt * 64 + k4 * 4];
                int ln = (r & 15) + 16 * oct;
                int rt = r >> 4;
                int idx = ((rt * 2 + ks) * 64 + ln) * 8 + koff;
                uint2 p;
                p.x = bf16pack2(v.x, v.y);
                p.y = bf16pack2(v.z, v.w);
                *(uint2*)&Al[idx] = p;
            }
        }
        // stage B: linear 16KB copy of precomputed fragment-order tile
        {
            const uint4* src = (const uint4*)wfrag + kt * 1024;
            uint4* dstp = (uint4*)Bl;
#pragma unroll
            for (int i = 0; i < 4; ++i) dstp[t + i * 256] = src[t + i * 256];
        }
        __syncthreads();
        bf16x8 a0 = *(const bf16x8*)&Al[(w * 2 + 0) * 512 + lane * 8];
        bf16x8 a1 = *(const bf16x8*)&Al[(w * 2 + 1) * 512 + lane * 8];
#pragma unroll
        for (int nt = 0; nt < 8; ++nt) {
            bf16x8 b0 = *(const bf16x8*)&Bl[(nt * 2 + 0) * 512 + lane * 8];
            bf16x8 b1 = *(const bf16x8*)&Bl[(nt * 2 + 1) * 512 + lane * 8];
            acc[nt] = __builtin_amdgcn_mfma_f32_16x16x32_bf16(a0, b0, acc[nt], 0, 0, 0);
            acc[nt] = __builtin_amdgcn_mfma_f32_16x16x32_bf16(a1, b1, acc[nt], 0, 0, 0);
        }
        __syncthreads();
    }

    // epilogue: C layout col=lane&15, row=(lane>>4)*4+reg  [m89-verified]
    const int col = lane & 15, g = lane >> 4;
    const int rbase = row0 + w * 16 + g * 4;
#pragma unroll
    for (int nt = 0; nt < 8; ++nt) {
        float asv = att_src[nt * 16 + col];
        float adv = att_dst[nt * 16 + col];
        const size_t hb = (size_t)nt * n;
#pragma unroll
        for (int reg = 0; reg < 4; ++reg) {
            int row = rbase + reg;
            float hv = acc[nt][reg];
            if (row < n) h1h[(hb + row) * 16 + col] = (unsigned short)bf16r(hv);
            float ps = hv * asv, pd = hv * adv;
            ps += __shfl_xor(ps, 1); ps += __shfl_xor(ps, 2);
            ps += __shfl_xor(ps, 4); ps += __shfl_xor(ps, 8);
            pd += __shfl_xor(pd, 1); pd += __shfl_xor(pd, 2);
            pd += __shfl_xor(pd, 4); pd += __shfl_xor(pd, 8);
            if (col == 0 && row < n) {
                a_srcH[hb + row] = ps;
                a_dstH[hb + row] = pd;
            }
        }
    }
}

// ---------------- CSR build ----------------
__global__ __launch_bounds__(256) void histrank_kernel(const int* __restrict__ ei, int E, int Etot,
                                                       int* __restrict__ counts,
                                                       int* __restrict__ rank)
{
    const int base = blockIdx.x * 2048 + threadIdx.x;
#pragma unroll
    for (int q = 0; q < 8; ++q) {
        int i = base + q * 256;
        if (i < Etot) {
            int dst = (i < E) ? ei[E + i] : (i - E);
            rank[i] = atomicAdd(&counts[dst], 1);
        }
    }
}

__global__ __launch_bounds__(256) void scan1_kernel(const int* __restrict__ counts,
                                                    int* __restrict__ bsum, int n)
{
    __shared__ int lds[256];
    const int t = threadIdx.x;
    const int base = blockIdx.x * 1024 + t * 4;
    int s = 0;
#pragma unroll
    for (int q = 0; q < 4; ++q) { int i = base + q; if (i < n) s += counts[i]; }
    lds[t] = s;
    __syncthreads();
#pragma unroll
    for (int off = 128; off > 0; off >>= 1) {
        if (t < off) lds[t] += lds[t + off];
        __syncthreads();
    }
    if (t == 0) bsum[blockIdx.x] = lds[0];
}

__global__ __launch_bounds__(256) void scan2_kernel(const int* __restrict__ bsum,
                                                    int* __restrict__ boffs, int nb,
                                                    int* __restrict__ indptr, int n, int Etot)
{
    __shared__ int lds[256];
    const int t = threadIdx.x;
    lds[t] = (t < nb) ? bsum[t] : 0;
    __syncthreads();
    for (int off = 1; off < 256; off <<= 1) {
        int v = (t >= off) ? lds[t - off] : 0;
        __syncthreads();
        lds[t] += v;
        __syncthreads();
    }
    if (t < nb) boffs[t] = (t == 0) ? 0 : lds[t - 1];
    if (t == 0) indptr[n] = Etot;
}

__global__ __launch_bounds__(256) void scan3_kernel(const int* __restrict__ counts,
                                                    const int* __restrict__ boffs,
                                                    int* __restrict__ indptr, int n)
{
    __shared__ int lds[256];
    const int t = threadIdx.x;
    const int base = blockIdx.x * 1024 + t * 4;
    int c[4];
    int s = 0;
#pragma unroll
    for (int q = 0; q < 4; ++q) {
        int i = base + q;
        c[q] = (i < n) ? counts[i] : 0;
        s += c[q];
    }
    lds[t] = s;
    __syncthreads();
    for (int off = 1; off < 256; off <<= 1) {
        int v = (t >= off) ? lds[t - off] : 0;
        __syncthreads();
        lds[t] += v;
        __syncthreads();
    }
    int run = boffs[blockIdx.x] + lds[t] - s;
#pragma unroll
    for (int q = 0; q < 4; ++q) {
        int i = base + q;
        if (i < n) indptr[i] = run;
        run += c[q];
    }
}

__global__ __launch_bounds__(256) void fill_kernel(const int* __restrict__ ei, int E, int Etot,
                                                   const int* __restrict__ indptr,
                                                   const int* __restrict__ rank,
                                                   int* __restrict__ sorted_src)
{
    const int base = blockIdx.x * 2048 + threadIdx.x;
#pragma unroll
    for (int q = 0; q < 8; ++q) {
        int i = base + q * 256;
        if (i < Etot) {
            int src, dst;
            if (i < E) { src = ei[i]; dst = ei[E + i]; }
            else       { src = i - E; dst = i - E; }
            sorted_src[indptr[dst] + rank[i]] = src;
        }
    }
}

// ---------------- layer-1 aggregation: HEAD-SPLIT for per-XCD L2 residency ----------------
// Block b: head = b&7 (XCD round-robin heuristic), dst chunk = b>>3 (32 dsts).
// Wave: 8 dsts x 8 lanes x 2 channels. Per-head slice of h1h = 3.2MB -> fits 4MB L2.
// Correct under ANY block->XCD mapping; the %8 trick only affects locality.
__global__ __launch_bounds__(256) void agg1_kernel(const unsigned* __restrict__ h1hu,
        const float* __restrict__ a_srcH, const float* __restrict__ a_dstH,
        const int* __restrict__ indptr, const int* __restrict__ ssrc,
        const float* __restrict__ b1, unsigned* __restrict__ out1h, int n)
{
    const int head = blockIdx.x & 7;
    const int chunk = blockIdx.x >> 3;
    const int wave = threadIdx.x >> 6, lane = threadIdx.x & 63;
    const int grp = lane >> 3, cl = lane & 7;      // dst-group, channel-pair
    const int dst = chunk * 32 + wave * 8 + grp;
    const bool valid = dst < n;
    const size_t hb = (size_t)head * n;
    float ad = 0.f;
    int j = 0, end = 0;
    if (valid) {
        ad = a_dstH[hb + dst];
        j = indptr[dst];
        end = indptr[dst + 1];
    }
    float s0 = 0.f, s1 = 0.f, s2 = 0.f, s3 = 0.f;
    float ax0 = 0.f, ay0 = 0.f, ax1 = 0.f, ay1 = 0.f;
    float ax2 = 0.f, ay2 = 0.f, ax3 = 0.f, ay3 = 0.f;
    while (__any(j < end)) {
        bool a0 = j < end, a1 = j + 1 < end, a2 = j + 2 < end, a3 = j + 3 < end;
        int sc0 = a0 ? ssrc[j]     : 0;
        int sc1 = a1 ? ssrc[j + 1] : 0;
        int sc2 = a2 ? ssrc[j + 2] : 0;
        int sc3 = a3 ? ssrc[j + 3] : 0;
        float as0 = a_srcH[hb + sc0];
        float as1 = a_srcH[hb + sc1];
        float as2 = a_srcH[hb + sc2];
        float as3 = a_srcH[hb + sc3];
        unsigned v0 = h1hu[(hb + sc0) * 8 + cl];
        unsigned v1 = h1hu[(hb + sc1) * 8 + cl];
        unsigned v2 = h1hu[(hb + sc2) * 8 + cl];
        unsigned v3 = h1hu[(hb + sc3) * 8 + cl];
        float p0 = a0 ? __expf(lrelu(as0 + ad)) : 0.f;
        float p1 = a1 ? __expf(lrelu(as1 + ad)) : 0.f;
        float p2 = a2 ? __expf(lrelu(as2 + ad)) : 0.f;
        float p3 = a3 ? __expf(lrelu(as3 + ad)) : 0.f;
        float2 h0 = bf2unpack(v0), h1v = bf2unpack(v1);
        float2 h2v = bf2unpack(v2), h3v = bf2unpack(v3);
        s0 += p0; ax0 += p0 * h0.x;  ay0 += p0 * h0.y;
        s1 += p1; ax1 += p1 * h1v.x; ay1 += p1 * h1v.y;
        s2 += p2; ax2 += p2 * h2v.x; ay2 += p2 * h2v.y;
        s3 += p3; ax3 += p3 * h3v.x; ay3 += p3 * h3v.y;
        j += 4;
    }
    if (valid) {
        float s = (s0 + s1) + (s2 + s3);
        float ax = (ax0 + ax1) + (ax2 + ax3);
        float ay = (ay0 + ay1) + (ay2 + ay3);
        float inv = 1.f / (s + 1e-16f);
        float2 bb = *(const float2*)&b1[head * 16 + cl * 2];
        float ox = fmaxf(ax * inv + bb.x, 0.f);   // fused ReLU
        float oy = fmaxf(ay * inv + bb.y, 0.f);
        out1h[(hb + dst) * 8 + cl] = bf16pack2(ox, oy);
    }
}

// ---------------- GEMM2 + layer-2 attention logits (head-split bf16 in, bf16 h2 out) ----------------
__global__ __launch_bounds__(256) void gemm2_kernel(const unsigned* __restrict__ out1h,
        const float* __restrict__ W2, const float* __restrict__ atts2,
        const float* __restrict__ attd2,
        unsigned short* __restrict__ h2us, float* __restrict__ a_src, float* __restrict__ a_dst, int n)
{
    __shared__ float wl[128][NCLS];    // 20,480B
    __shared__ float xs[64][68];       // 17,408B
    const int t = threadIdx.x;
    const int row0 = blockIdx.x * 64;
    const int rg = t >> 3;            // rows 2rg, 2rg+1
    const int cg = t & 7;             // cols 5cg..5cg+4
    const int r0 = rg * 2;

#pragma unroll
    for (int i = t; i < 1280; i += 256)
        *(float4*)&wl[0][0 + i * 4] = *(const float4*)&W2[i * 4];

    float acc[2][5];
#pragma unroll
    for (int i = 0; i < 2; ++i)
#pragma unroll
        for (int j = 0; j < 5; ++j) acc[i][j] = 0.f;

    for (int kh = 0; kh < 2; ++kh) {
        // stage x half-tile from head-split bf16: uint pair index u = kh*32 + u2*2
#pragma unroll
        for (int i = t; i < 1024; i += 256) {
            int r = i >> 4, u2 = i & 15;
            int gr = row0 + r;
            float4 v = make_float4(0.f, 0.f, 0.f, 0.f);
            if (gr < n) {
                int u = kh * 32 + u2 * 2;
                int hh = u >> 3, cc = u & 7;
                uint2 pk = *(const uint2*)&out1h[((size_t)hh * n + gr) * 8 + cc];
                float2 ab = bf2unpack(pk.x);
                float2 cd = bf2unpack(pk.y);
                v = make_float4(ab.x, ab.y, cd.x, cd.y);
            }
            *(float4*)&xs[r][u2 * 4] = v;
        }
        __syncthreads();
#pragma unroll 4
        for (int k = 0; k < 64; ++k) {
            float xa = xs[r0][k];
            float xb = xs[r0 + 1][k];
            const float* wr = &wl[kh * 64 + k][cg * 5];
#pragma unroll
            for (int j = 0; j < 5; ++j) {
                float w = wr[j];
                acc[0][j] += xa * w;
                acc[1][j] += xb * w;
            }
        }
        __syncthreads();
    }

    float as5[5], ad5[5];
#pragma unroll
    for (int j = 0; j < 5; ++j) {
        as5[j] = atts2[cg * 5 + j];
        ad5[j] = attd2[cg * 5 + j];
    }
#pragma unroll
    for (int i = 0; i < 2; ++i) {
        int row = row0 + r0 + i;
        if (row >= n) break;
#pragma unroll
        for (int j = 0; j < 5; ++j)
            h2us[(size_t)row * NCLS + cg * 5 + j] = (unsigned short)bf16r(acc[i][j]);
        float ps = acc[i][0] * as5[0] + acc[i][1] * as5[1] + acc[i][2] * as5[2]
                 + acc[i][3] * as5[3] + acc[i][4] * as5[4];
        float pd = acc[i][0] * ad5[0] + acc[i][1] * ad5[1] + acc[i][2] * ad5[2]
                 + acc[i][3] * ad5[3] + acc[i][4] * ad5[4];
        ps += __shfl_xor(ps, 1); ps += __shfl_xor(ps, 2); ps += __shfl_xor(ps, 4);
        pd += __shfl_xor(pd, 1); pd += __shfl_xor(pd, 2); pd += __shfl_xor(pd, 4);
        if (cg == 0) { a_src[row] = ps; a_dst[row] = pd; }
    }
}

// ---------------- layer-2 aggregation: 3 dsts/wave, bf16 gathers, 4-way unroll ----------------
__global__ __launch_bounds__(256) void agg2_kernel(const unsigned* __restrict__ h2b,
        const float* __restrict__ a_src, const float* __restrict__ a_dst,
        const int* __restrict__ indptr, const int* __restrict__ ssrc,
        const float* __restrict__ b2, float* __restrict__ out, int n)
{
    const int wave = threadIdx.x >> 6, lane = threadIdx.x & 63;
    const int grp = lane / 20;            // 0..2 (lanes 60..63 idle)
    const int sub = lane - grp * 20;      // classes sub*2, sub*2+1
    const int dst = blockIdx.x * 12 + wave * 3 + grp;
    const bool valid = (grp < 3) && (dst < n);
    const float ad = valid ? a_dst[dst] : 0.f;
    int beg = 0, end = 0;
    if (valid) { beg = indptr[dst]; end = indptr[dst + 1]; }
    float s0 = 0.f, s1 = 0.f, s2 = 0.f, s3 = 0.f;
    float ax0 = 0.f, ay0 = 0.f, ax1 = 0.f, ay1 = 0.f;
    float ax2 = 0.f, ay2 = 0.f, ax3 = 0.f, ay3 = 0.f;
    int j = beg;
    for (; j + 4 <= end; j += 4) {
        int sc0 = ssrc[j], sc1 = ssrc[j + 1], sc2 = ssrc[j + 2], sc3 = ssrc[j + 3];
        float p0 = __expf(lrelu(a_src[sc0] + ad));
        float p1 = __expf(lrelu(a_src[sc1] + ad));
        float p2 = __expf(lrelu(a_src[sc2] + ad));
        float p3 = __expf(lrelu(a_src[sc3] + ad));
        float2 h0 = bf2unpack(h2b[(size_t)sc0 * 20 + sub]);
        float2 h1v = bf2unpack(h2b[(size_t)sc1 * 20 + sub]);
        float2 h2v = bf2unpack(h2b[(size_t)sc2 * 20 + sub]);
        float2 h3v = bf2unpack(h2b[(size_t)sc3 * 20 + sub]);
        s0 += p0; ax0 += p0 * h0.x;  ay0 += p0 * h0.y;
        s1 += p1; ax1 += p1 * h1v.x; ay1 += p1 * h1v.y;
        s2 += p2; ax2 += p2 * h2v.x; ay2 += p2 * h2v.y;
        s3 += p3; ax3 += p3 * h3v.x; ay3 += p3 * h3v.y;
    }
    for (; j < end; ++j) {
        int sc = ssrc[j];
        float p = __expf(lrelu(a_src[sc] + ad));
        float2 hv = bf2unpack(h2b[(size_t)sc * 20 + sub]);
        s0 += p; ax0 += p * hv.x; ay0 += p * hv.y;
    }
    if (valid) {
        float s = (s0 + s1) + (s2 + s3);
        float accx = (ax0 + ax1) + (ax2 + ax3);
        float accy = (ay0 + ay1) + (ay2 + ay3);
        float inv = 1.f / (s + 1e-16f);
        float2 o;
        o.x = accx * inv + b2[sub * 2];
        o.y = accy * inv + b2[sub * 2 + 1];
        *(float2*)&out[(size_t)dst * NCLS + sub * 2] = o;
    }
}

extern "C" void kernel_launch(void* const* d_in, const int* in_sizes, int n_in,
                              void* d_out, int out_size, void* d_ws, size_t ws_size,
                              hipStream_t stream)
{
    const float* x   = (const float*)d_in[0];
    const int*   ei  = (const int*)d_in[1];   // edge_index, int32 per harness contract
    const float* W1  = (const float*)d_in[2];
    const float* as1 = (const float*)d_in[3];
    const float* ad1 = (const float*)d_in[4];
    const float* b1  = (const float*)d_in[5];
    const float* W2  = (const float*)d_in[6];
    const float* as2 = (const float*)d_in[7];
    const float* ad2 = (const float*)d_in[8];
    const float* b2  = (const float*)d_in[9];
    float* out = (float*)d_out;

    const int n    = in_sizes[0] / KF;   // 100000
    const int E    = in_sizes[1] / 2;    // 1600000
    const int Etot = E + n;              // + self loops

    // workspace layout (16B aligned)
    char* ws = (char*)d_ws;
    unsigned* h1b   = (unsigned*)ws;                   // 25.6 MB  head-split [8][n][8 uint]
    unsigned* out1b = (unsigned*)(ws + 25600000);      // 25.6 MB  head-split [8][n][8 uint]
    float* a_s1     = (float*)(ws + 51200000);         // 3.2 MB   [8][n]
    float* a_d1     = (float*)(ws + 54400000);         // 3.2 MB   [8][n]
    int*   indptr   = (int*)  (ws + 57600000);         // [n+1]
    int*   counts   = (int*)  (ws + 58000016);         // [n]
    int*   ssrc     = (int*)  (ws + 58400016);         // 6.8 MB   [Etot]
    unsigned short* wfrag = (unsigned short*)(ws + 65200016);  // 64 KB W1 frag-order bf16
    int*   rank     = (int*)  (ws + 65270016);         // 6.8 MB   [Etot]
    int*   bsum     = (int*)  (ws + 72070016);
    int*   boffs    = (int*)  (ws + 72074112);
    // layer-2 buffers alias h1b region (h1b dead after agg1; gemm2 runs after agg1)
    unsigned* h2b   = (unsigned*)ws;                   // 8 MB     [n,20] bf16x2
    float* a_s2     = (float*)(ws + 8000000);          // 400 KB
    float* a_d2     = (float*)(ws + 8400000);          // 400 KB

    const int nb = (n + 1023) / 1024;    // 98 scan chunks (<= 256)
    dim3 b256(256);

    hipMemsetAsync(counts, 0, n * sizeof(int), stream);
    wprep_kernel<<<dim3((KF * F1 + 255) / 256), b256, 0, stream>>>(W1, wfrag);
    gemm1_kernel<<<dim3((n + BM - 1) / BM), b256, 0, stream>>>(x, wfrag, as1, ad1,
                                                               (unsigned short*)h1b, a_s1, a_d1, n);
    histrank_kernel<<<dim3((Etot + 2047) / 2048), b256, 0, stream>>>(ei, E, Etot, counts, rank);
    scan1_kernel<<<dim3(nb), b256, 0, stream>>>(counts, bsum, n);
    scan2_kernel<<<dim3(1), b256, 0, stream>>>(bsum, boffs, nb, indptr, n, Etot);
    scan3_kernel<<<dim3(nb), b256, 0, stream>>>(counts, boffs, indptr, n);
    fill_kernel<<<dim3((Etot + 2047) / 2048), b256, 0, stream>>>(ei, E, Etot, indptr, rank, ssrc);
    agg1_kernel<<<dim3(((n + 31) / 32) * 8), b256, 0, stream>>>(h1b, a_s1, a_d1, indptr, ssrc,
                                                                b1, out1b, n);
    gemm2_kernel<<<dim3((n + 63) / 64), b256, 0, stream>>>(out1b, W2, as2, ad2,
                                                           (unsigned short*)h2b, a_s2, a_d2, n);
    agg2_kernel<<<dim3((n + 11) / 12), b256, 0, stream>>>(h2b, a_s2, a_d2, indptr, ssrc, b2, out, n);
}

// Round 15
// 332.961 us; speedup vs baseline: 1.2011x; 1.2011x over previous
//
#include <hip/hip_runtime.h>
#include <math.h>

#define KF 256      // input features
#define F1 128      // layer-1 hidden (8 heads x 16)
#define NH 8        // heads layer 1
#define NC 16       // channels per head layer 1
#define NCLS 40     // layer-2 output classes
#define NEG 0.2f    // leaky relu slope
#define BM 128      // gemm1 row tile (2 row-tiles per wave)

static __device__ __forceinline__ float lrelu(float v) { return fmaxf(v, NEG * v); }

// round-to-nearest-even bf16 packing helpers
static __device__ __forceinline__ unsigned bf16r(float a) {
    unsigned u = __float_as_uint(a);
    return (u + 0x7fffu + ((u >> 16) & 1u)) >> 16;
}
static __device__ __forceinline__ unsigned bf16pack2(float a, float b) {
    return bf16r(a) | (bf16r(b) << 16);
}
static __device__ __forceinline__ float2 bf2unpack(unsigned v) {
    float2 r;
    r.x = __uint_as_float(v << 16);
    r.y = __uint_as_float(v & 0xffff0000u);
    return r;
}

typedef __attribute__((ext_vector_type(8))) short bf16x8;
typedef __attribute__((ext_vector_type(4))) float f32x4;

// ---------------- W1 -> bf16 B-fragment-order buffer (one-time prep) ----------------
// B-frag (16x16x32): lane = (n&15) + 16*((k&31)>>3), elem e = k&7.
// wfrag u16 index = (((kt*8 + nt)*2 + ks)*64 + lane)*8 + e, kt=k>>6, ks=(k>>5)&1, nt=n>>4.
__global__ __launch_bounds__(256) void wprep_kernel(const float* __restrict__ W1,
                                                    unsigned short* __restrict__ wfrag)
{
    int gid = blockIdx.x * 256 + threadIdx.x;
    if (gid >= KF * F1) return;
    int k = gid >> 7, nn = gid & 127;
    int kt = k >> 6, ks = (k >> 5) & 1, oct = (k >> 3) & 3, e = k & 7;
    int nt = nn >> 4, ln = (nn & 15) + 16 * oct;
    int idx = (((kt * 8 + nt) * 2 + ks) * 64 + ln) * 8 + e;
    wfrag[idx] = (unsigned short)bf16r(W1[gid]);
}

// ---------------- GEMM1 (MFMA bf16) + fused attention logits ----------------
// Round-8 structure, BM=128: 4 waves, wave w owns row-tiles {2w, 2w+1} x all 8 nt.
// Per kt: stage A (16KB) + B (16KB), 32 MFMA/wave -> 2x compute per barrier vs BM=64.
__global__ __launch_bounds__(256) void gemm1_kernel(const float* __restrict__ x,
        const unsigned short* __restrict__ wfrag,
        const float* __restrict__ att_src, const float* __restrict__ att_dst,
        unsigned short* __restrict__ h1u, float* __restrict__ a_src, float* __restrict__ a_dst, int n)
{
    __shared__ __align__(16) unsigned short Al[8192];  // A 128x64 frag-order, 16KB
    __shared__ __align__(16) unsigned short Bl[8192];  // B 64x128 frag-order, 16KB
    const int t = threadIdx.x;
    const int w = t >> 6, lane = t & 63;
    const int row0 = blockIdx.x * BM;

    f32x4 acc[2][8];
#pragma unroll
    for (int i = 0; i < 2; ++i)
#pragma unroll
        for (int j = 0; j < 8; ++j) acc[i][j] = (f32x4){0.f, 0.f, 0.f, 0.f};

    for (int kt = 0; kt < 4; ++kt) {
        // stage A: x[row0..+128][kt*64..+64] -> bf16 fragment order
        {
            const int k4 = t & 15;
            const int ks = k4 >> 3;
            const int oct = (k4 >> 1) & 3;
            const int koff = (k4 & 1) * 4;
#pragma unroll
            for (int it = 0; it < 8; ++it) {
                int r = (t >> 4) + it * 16;
                int gr = row0 + r;
                float4 v = make_float4(0.f, 0.f, 0.f, 0.f);
                if (gr < n) v = *(const float4*)&x[(size_t)gr * KF + kt * 64 + k4 * 4];
                int ln = (r & 15) + 16 * oct;
                int rt = r >> 4;     // 0..7
                int idx = ((rt * 2 + ks) * 64 + ln) * 8 + koff;
                uint2 p;
                p.x = bf16pack2(v.x, v.y);
                p.y = bf16pack2(v.z, v.w);
                *(uint2*)&Al[idx] = p;
            }
        }
        // stage B: linear 16KB copy of precomputed fragment-order tile
        {
            const uint4* src = (const uint4*)wfrag + kt * 1024;
            uint4* dstp = (uint4*)Bl;
#pragma unroll
            for (int i = 0; i < 4; ++i) dstp[t + i * 256] = src[t + i * 256];
        }
        __syncthreads();
        bf16x8 a00 = *(const bf16x8*)&Al[(((2 * w    ) * 2 + 0) * 64 + lane) * 8];
        bf16x8 a01 = *(const bf16x8*)&Al[(((2 * w    ) * 2 + 1) * 64 + lane) * 8];
        bf16x8 a10 = *(const bf16x8*)&Al[(((2 * w + 1) * 2 + 0) * 64 + lane) * 8];
        bf16x8 a11 = *(const bf16x8*)&Al[(((2 * w + 1) * 2 + 1) * 64 + lane) * 8];
#pragma unroll
        for (int nt = 0; nt < 8; ++nt) {
            bf16x8 b0 = *(const bf16x8*)&Bl[(nt * 2 + 0) * 512 + lane * 8];
            bf16x8 b1 = *(const bf16x8*)&Bl[(nt * 2 + 1) * 512 + lane * 8];
            acc[0][nt] = __builtin_amdgcn_mfma_f32_16x16x32_bf16(a00, b0, acc[0][nt], 0, 0, 0);
            acc[0][nt] = __builtin_amdgcn_mfma_f32_16x16x32_bf16(a01, b1, acc[0][nt], 0, 0, 0);
            acc[1][nt] = __builtin_amdgcn_mfma_f32_16x16x32_bf16(a10, b0, acc[1][nt], 0, 0, 0);
            acc[1][nt] = __builtin_amdgcn_mfma_f32_16x16x32_bf16(a11, b1, acc[1][nt], 0, 0, 0);
        }
        __syncthreads();
    }

    // epilogue: C layout col=lane&15, row=(lane>>4)*4+reg  [m89-verified]
    const int col = lane & 15, g = lane >> 4;
#pragma unroll
    for (int i = 0; i < 2; ++i) {
        const int rbase = row0 + (2 * w + i) * 16 + g * 4;
#pragma unroll
        for (int nt = 0; nt < 8; ++nt) {
            float asv = att_src[nt * 16 + col];
            float adv = att_dst[nt * 16 + col];
#pragma unroll
            for (int reg = 0; reg < 4; ++reg) {
                int row = rbase + reg;
                float hv = acc[i][nt][reg];
                if (row < n) h1u[(size_t)row * F1 + nt * 16 + col] = (unsigned short)bf16r(hv);
                float ps = hv * asv, pd = hv * adv;
                ps += __shfl_xor(ps, 1); ps += __shfl_xor(ps, 2);
                ps += __shfl_xor(ps, 4); ps += __shfl_xor(ps, 8);
                pd += __shfl_xor(pd, 1); pd += __shfl_xor(pd, 2);
                pd += __shfl_xor(pd, 4); pd += __shfl_xor(pd, 8);
                if (col == 0 && row < n) {
                    a_src[row * NH + nt] = ps;
                    a_dst[row * NH + nt] = pd;
                }
            }
        }
    }
}

// ---------------- CSR build ----------------
__global__ __launch_bounds__(256) void histrank_kernel(const int* __restrict__ ei, int E, int Etot,
                                                       int* __restrict__ counts,
                                                       int* __restrict__ rank)
{
    const int base = blockIdx.x * 2048 + threadIdx.x;
#pragma unroll
    for (int q = 0; q < 8; ++q) {
        int i = base + q * 256;
        if (i < Etot) {
            int dst = (i < E) ? ei[E + i] : (i - E);
            rank[i] = atomicAdd(&counts[dst], 1);
        }
    }
}

__global__ __launch_bounds__(256) void scan1_kernel(const int* __restrict__ counts,
                                                    int* __restrict__ bsum, int n)
{
    __shared__ int lds[256];
    const int t = threadIdx.x;
    const int base = blockIdx.x * 1024 + t * 4;
    int s = 0;
#pragma unroll
    for (int q = 0; q < 4; ++q) { int i = base + q; if (i < n) s += counts[i]; }
    lds[t] = s;
    __syncthreads();
#pragma unroll
    for (int off = 128; off > 0; off >>= 1) {
        if (t < off) lds[t] += lds[t + off];
        __syncthreads();
    }
    if (t == 0) bsum[blockIdx.x] = lds[0];
}

__global__ __launch_bounds__(256) void scan2_kernel(const int* __restrict__ bsum,
                                                    int* __restrict__ boffs, int nb,
                                                    int* __restrict__ indptr, int n, int Etot)
{
    __shared__ int lds[256];
    const int t = threadIdx.x;
    lds[t] = (t < nb) ? bsum[t] : 0;
    __syncthreads();
    for (int off = 1; off < 256; off <<= 1) {
        int v = (t >= off) ? lds[t - off] : 0;
        __syncthreads();
        lds[t] += v;
        __syncthreads();
    }
    if (t < nb) boffs[t] = (t == 0) ? 0 : lds[t - 1];
    if (t == 0) indptr[n] = Etot;
}

__global__ __launch_bounds__(256) void scan3_kernel(const int* __restrict__ counts,
                                                    const int* __restrict__ boffs,
                                                    int* __restrict__ indptr, int n)
{
    __shared__ int lds[256];
    const int t = threadIdx.x;
    const int base = blockIdx.x * 1024 + t * 4;
    int c[4];
    int s = 0;
#pragma unroll
    for (int q = 0; q < 4; ++q) {
        int i = base + q;
        c[q] = (i < n) ? counts[i] : 0;
        s += c[q];
    }
    lds[t] = s;
    __syncthreads();
    for (int off = 1; off < 256; off <<= 1) {
        int v = (t >= off) ? lds[t - off] : 0;
        __syncthreads();
        lds[t] += v;
        __syncthreads();
    }
    int run = boffs[blockIdx.x] + lds[t] - s;
#pragma unroll
    for (int q = 0; q < 4; ++q) {
        int i = base + q;
        if (i < n) indptr[i] = run;
        run += c[q];
    }
}

__global__ __launch_bounds__(256) void fill_kernel(const int* __restrict__ ei, int E, int Etot,
                                                   const int* __restrict__ indptr,
                                                   const int* __restrict__ rank,
                                                   int* __restrict__ sorted_src)
{
    const int base = blockIdx.x * 2048 + threadIdx.x;
#pragma unroll
    for (int q = 0; q < 8; ++q) {
        int i = base + q * 256;
        if (i < Etot) {
            int src, dst;
            if (i < E) { src = ei[i]; dst = ei[E + i]; }
            else       { src = i - E; dst = i - E; }
            sorted_src[indptr[dst] + rank[i]] = src;
        }
    }
}

// ---------------- layer-1 aggregation: wave/dst, bf16 gathers, 4-way unroll ----------------
// (round-10 form: measured 91 us, VALU-issue-bound)
__global__ __launch_bounds__(256) void agg1_kernel(const unsigned* __restrict__ h1b,
        const float* __restrict__ a_src, const float* __restrict__ a_dst,
        const int* __restrict__ indptr, const int* __restrict__ ssrc,
        const float* __restrict__ b1, unsigned* __restrict__ out1b, int n)
{
    const int wave = threadIdx.x >> 6, lane = threadIdx.x & 63;
    const int dst = blockIdx.x * 4 + wave;
    if (dst >= n) return;
    const int h = lane >> 3;              // head (2 channels/lane, 8 lanes/head)
    const float ad = a_dst[dst * NH + h];
    const int beg = indptr[dst], end = indptr[dst + 1];
    float s0 = 0.f, s1 = 0.f, s2 = 0.f, s3 = 0.f;
    float ax0 = 0.f, ay0 = 0.f, ax1 = 0.f, ay1 = 0.f;
    float ax2 = 0.f, ay2 = 0.f, ax3 = 0.f, ay3 = 0.f;
    int j = beg;
    for (; j + 4 <= end; j += 4) {
        int sc0 = ssrc[j], sc1 = ssrc[j + 1], sc2 = ssrc[j + 2], sc3 = ssrc[j + 3];
        float as0 = a_src[sc0 * NH + h];
        float as1 = a_src[sc1 * NH + h];
        float as2 = a_src[sc2 * NH + h];
        float as3 = a_src[sc3 * NH + h];
        unsigned v0 = h1b[(size_t)sc0 * 64 + lane];
        unsigned v1 = h1b[(size_t)sc1 * 64 + lane];
        unsigned v2 = h1b[(size_t)sc2 * 64 + lane];
        unsigned v3 = h1b[(size_t)sc3 * 64 + lane];
        float p0 = __expf(lrelu(as0 + ad));
        float p1 = __expf(lrelu(as1 + ad));
        float p2 = __expf(lrelu(as2 + ad));
        float p3 = __expf(lrelu(as3 + ad));
        float2 hv0 = bf2unpack(v0), hv1 = bf2unpack(v1);
        float2 hv2 = bf2unpack(v2), hv3 = bf2unpack(v3);
        s0 += p0; ax0 += p0 * hv0.x; ay0 += p0 * hv0.y;
        s1 += p1; ax1 += p1 * hv1.x; ay1 += p1 * hv1.y;
        s2 += p2; ax2 += p2 * hv2.x; ay2 += p2 * hv2.y;
        s3 += p3; ax3 += p3 * hv3.x; ay3 += p3 * hv3.y;
    }
    for (; j < end; ++j) {
        int sc = ssrc[j];
        float as = a_src[sc * NH + h];
        float2 hv = bf2unpack(h1b[(size_t)sc * 64 + lane]);
        float p = __expf(lrelu(as + ad));
        s0 += p; ax0 += p * hv.x; ay0 += p * hv.y;
    }
    float s = (s0 + s1) + (s2 + s3);
    float accx = (ax0 + ax1) + (ax2 + ax3);
    float accy = (ay0 + ay1) + (ay2 + ay3);
    float inv = 1.f / (s + 1e-16f);
    float2 bb = *(const float2*)&b1[lane * 2];
    float ox = fmaxf(accx * inv + bb.x, 0.f);   // fused ReLU
    float oy = fmaxf(accy * inv + bb.y, 0.f);
    out1b[(size_t)dst * 64 + lane] = bf16pack2(ox, oy);
}

// ---------------- GEMM2 + layer-2 attention logits (bf16 in, bf16 h2 out) ----------------
__global__ __launch_bounds__(256) void gemm2_kernel(const unsigned* __restrict__ out1b,
        const float* __restrict__ W2, const float* __restrict__ atts2,
        const float* __restrict__ attd2,
        unsigned short* __restrict__ h2us, float* __restrict__ a_src, float* __restrict__ a_dst, int n)
{
    __shared__ float wl[128][NCLS];    // 20,480B
    __shared__ float xs[64][68];       // 17,408B
    const int t = threadIdx.x;
    const int row0 = blockIdx.x * 64;
    const int rg = t >> 3;            // rows 2rg, 2rg+1
    const int cg = t & 7;             // cols 5cg..5cg+4
    const int r0 = rg * 2;

#pragma unroll
    for (int i = t; i < 1280; i += 256)
        *(float4*)&wl[0][0 + i * 4] = *(const float4*)&W2[i * 4];

    float acc[2][5];
#pragma unroll
    for (int i = 0; i < 2; ++i)
#pragma unroll
        for (int j = 0; j < 5; ++j) acc[i][j] = 0.f;

    for (int kh = 0; kh < 2; ++kh) {
        // stage x half-tile from bf16: 64 rows x 16 uint2 (4 channels each)
#pragma unroll
        for (int i = t; i < 1024; i += 256) {
            int r = i >> 4, u2 = i & 15;
            int gr = row0 + r;
            float4 v = make_float4(0.f, 0.f, 0.f, 0.f);
            if (gr < n) {
                uint2 pk = *(const uint2*)&out1b[(size_t)gr * 64 + kh * 32 + u2 * 2];
                float2 ab = bf2unpack(pk.x);
                float2 cd = bf2unpack(pk.y);
                v = make_float4(ab.x, ab.y, cd.x, cd.y);
            }
            *(float4*)&xs[r][u2 * 4] = v;
        }
        __syncthreads();
#pragma unroll 4
        for (int k = 0; k < 64; ++k) {
            float xa = xs[r0][k];
            float xb = xs[r0 + 1][k];
            const float* wr = &wl[kh * 64 + k][cg * 5];
#pragma unroll
            for (int j = 0; j < 5; ++j) {
                float w = wr[j];
                acc[0][j] += xa * w;
                acc[1][j] += xb * w;
            }
        }
        __syncthreads();
    }

    float as5[5], ad5[5];
#pragma unroll
    for (int j = 0; j < 5; ++j) {
        as5[j] = atts2[cg * 5 + j];
        ad5[j] = attd2[cg * 5 + j];
    }
#pragma unroll
    for (int i = 0; i < 2; ++i) {
        int row = row0 + r0 + i;
        if (row >= n) break;
#pragma unroll
        for (int j = 0; j < 5; ++j)
            h2us[(size_t)row * NCLS + cg * 5 + j] = (unsigned short)bf16r(acc[i][j]);
        float ps = acc[i][0] * as5[0] + acc[i][1] * as5[1] + acc[i][2] * as5[2]
                 + acc[i][3] * as5[3] + acc[i][4] * as5[4];
        float pd = acc[i][0] * ad5[0] + acc[i][1] * ad5[1] + acc[i][2] * ad5[2]
                 + acc[i][3] * ad5[3] + acc[i][4] * ad5[4];
        ps += __shfl_xor(ps, 1); ps += __shfl_xor(ps, 2); ps += __shfl_xor(ps, 4);
        pd += __shfl_xor(pd, 1); pd += __shfl_xor(pd, 2); pd += __shfl_xor(pd, 4);
        if (cg == 0) { a_src[row] = ps; a_dst[row] = pd; }
    }
}

// ---------------- layer-2 aggregation: 3 dsts/wave, bf16 gathers, 4-way unroll ----------------
__global__ __launch_bounds__(256) void agg2_kernel(const unsigned* __restrict__ h2b,
        const float* __restrict__ a_src, const float* __restrict__ a_dst,
        const int* __restrict__ indptr, const int* __restrict__ ssrc,
        const float* __restrict__ b2, float* __restrict__ out, int n)
{
    const int wave = threadIdx.x >> 6, lane = threadIdx.x & 63;
    const int grp = lane / 20;            // 0..2 (lanes 60..63 idle)
    const int sub = lane - grp * 20;      // classes sub*2, sub*2+1
    const int dst = blockIdx.x * 12 + wave * 3 + grp;
    const bool valid = (grp < 3) && (dst < n);
    const float ad = valid ? a_dst[dst] : 0.f;
    int beg = 0, end = 0;
    if (valid) { beg = indptr[dst]; end = indptr[dst + 1]; }
    float s0 = 0.f, s1 = 0.f, s2 = 0.f, s3 = 0.f;
    float ax0 = 0.f, ay0 = 0.f, ax1 = 0.f, ay1 = 0.f;
    float ax2 = 0.f, ay2 = 0.f, ax3 = 0.f, ay3 = 0.f;
    int j = beg;
    for (; j + 4 <= end; j += 4) {
        int sc0 = ssrc[j], sc1 = ssrc[j + 1], sc2 = ssrc[j + 2], sc3 = ssrc[j + 3];
        float p0 = __expf(lrelu(a_src[sc0] + ad));
        float p1 = __expf(lrelu(a_src[sc1] + ad));
        float p2 = __expf(lrelu(a_src[sc2] + ad));
        float p3 = __expf(lrelu(a_src[sc3] + ad));
        float2 h0 = bf2unpack(h2b[(size_t)sc0 * 20 + sub]);
        float2 h1v = bf2unpack(h2b[(size_t)sc1 * 20 + sub]);
        float2 h2v = bf2unpack(h2b[(size_t)sc2 * 20 + sub]);
        float2 h3v = bf2unpack(h2b[(size_t)sc3 * 20 + sub]);
        s0 += p0; ax0 += p0 * h0.x;  ay0 += p0 * h0.y;
        s1 += p1; ax1 += p1 * h1v.x; ay1 += p1 * h1v.y;
        s2 += p2; ax2 += p2 * h2v.x; ay2 += p2 * h2v.y;
        s3 += p3; ax3 += p3 * h3v.x; ay3 += p3 * h3v.y;
    }
    for (; j < end; ++j) {
        int sc = ssrc[j];
        float p = __expf(lrelu(a_src[sc] + ad));
        float2 hv = bf2unpack(h2b[(size_t)sc * 20 + sub]);
        s0 += p; ax0 += p * hv.x; ay0 += p * hv.y;
    }
    if (valid) {
        float s = (s0 + s1) + (s2 + s3);
        float accx = (ax0 + ax1) + (ax2 + ax3);
        float accy = (ay0 + ay1) + (ay2 + ay3);
        float inv = 1.f / (s + 1e-16f);
        float2 o;
        o.x = accx * inv + b2[sub * 2];
        o.y = accy * inv + b2[sub * 2 + 1];
        *(float2*)&out[(size_t)dst * NCLS + sub * 2] = o;
    }
}

extern "C" void kernel_launch(void* const* d_in, const int* in_sizes, int n_in,
                              void* d_out, int out_size, void* d_ws, size_t ws_size,
                              hipStream_t stream)
{
    const float* x   = (const float*)d_in[0];
    const int*   ei  = (const int*)d_in[1];   // edge_index, int32 per harness contract
    const float* W1  = (const float*)d_in[2];
    const float* as1 = (const float*)d_in[3];
    const float* ad1 = (const float*)d_in[4];
    const float* b1  = (const float*)d_in[5];
    const float* W2  = (const float*)d_in[6];
    const float* as2 = (const float*)d_in[7];
    const float* ad2 = (const float*)d_in[8];
    const float* b2  = (const float*)d_in[9];
    float* out = (float*)d_out;

    const int n    = in_sizes[0] / KF;   // 100000
    const int E    = in_sizes[1] / 2;    // 1600000
    const int Etot = E + n;              // + self loops

    // workspace layout (16B aligned)
    char* ws = (char*)d_ws;
    unsigned* h1b   = (unsigned*)ws;                   // 25.6 MB  [n,64] bf16x2
    unsigned* out1b = (unsigned*)(ws + 25600000);      // 25.6 MB  [n,64] bf16x2
    float* a_s1     = (float*)(ws + 51200000);         // 3.2 MB   [n,8]
    float* a_d1     = (float*)(ws + 54400000);         // 3.2 MB   [n,8]
    int*   indptr   = (int*)  (ws + 57600000);         // [n+1]
    int*   counts   = (int*)  (ws + 58000016);         // [n]
    int*   ssrc     = (int*)  (ws + 58400016);         // 6.8 MB   [Etot]
    unsigned short* wfrag = (unsigned short*)(ws + 65200016);  // 64 KB W1 frag-order bf16
    int*   rank     = (int*)  (ws + 65270016);         // 6.8 MB   [Etot]
    int*   bsum     = (int*)  (ws + 72070016);
    int*   boffs    = (int*)  (ws + 72074112);
    // layer-2 buffers alias h1b region (h1b dead after agg1; gemm2 runs after agg1)
    unsigned* h2b   = (unsigned*)ws;                   // 8 MB     [n,20] bf16x2
    float* a_s2     = (float*)(ws + 8000000);          // 400 KB
    float* a_d2     = (float*)(ws + 8400000);          // 400 KB

    const int nb = (n + 1023) / 1024;    // 98 scan chunks (<= 256)
    dim3 b256(256);

    hipMemsetAsync(counts, 0, n * sizeof(int), stream);
    wprep_kernel<<<dim3((KF * F1 + 255) / 256), b256, 0, stream>>>(W1, wfrag);
    gemm1_kernel<<<dim3((n + BM - 1) / BM), b256, 0, stream>>>(x, wfrag, as1, ad1,
                                                               (unsigned short*)h1b, a_s1, a_d1, n);
    histrank_kernel<<<dim3((Etot + 2047) / 2048), b256, 0, stream>>>(ei, E, Etot, counts, rank);
    scan1_kernel<<<dim3(nb), b256, 0, stream>>>(counts, bsum, n);
    scan2_kernel<<<dim3(1), b256, 0, stream>>>(bsum, boffs, nb, indptr, n, Etot);
    scan3_kernel<<<dim3(nb), b256, 0, stream>>>(counts, boffs, indptr, n);
    fill_kernel<<<dim3((Etot + 2047) / 2048), b256, 0, stream>>>(ei, E, Etot, indptr, rank, ssrc);
    agg1_kernel<<<dim3((n + 3) / 4), b256, 0, stream>>>(h1b, a_s1, a_d1, indptr, ssrc, b1, out1b, n);
    gemm2_kernel<<<dim3((n + 63) / 64), b256, 0, stream>>>(out1b, W2, as2, ad2,
                                                           (unsigned short*)h2b, a_s2, a_d2, n);
    agg2_kernel<<<dim3((n + 11) / 12), b256, 0, stream>>>(h2b, a_s2, a_d2, indptr, ssrc, b2, out, n);
}

// Round 16
// 321.320 us; speedup vs baseline: 1.2446x; 1.0362x over previous
//
#include <hip/hip_runtime.h>
#include <math.h>

#define KF 256      // input features
#define F1 128      // layer-1 hidden (8 heads x 16)
#define NH 8        // heads layer 1
#define NC 16       // channels per head layer 1
#define NCLS 40     // layer-2 output classes
#define NEG 0.2f    // leaky relu slope
#define BM 64       // gemm1 row tile

static __device__ __forceinline__ float lrelu(float v) { return fmaxf(v, NEG * v); }

// round-to-nearest-even bf16 packing helpers
static __device__ __forceinline__ unsigned bf16r(float a) {
    unsigned u = __float_as_uint(a);
    return (u + 0x7fffu + ((u >> 16) & 1u)) >> 16;
}
static __device__ __forceinline__ unsigned bf16pack2(float a, float b) {
    return bf16r(a) | (bf16r(b) << 16);
}
static __device__ __forceinline__ float2 bf2unpack(unsigned v) {
    float2 r;
    r.x = __uint_as_float(v << 16);
    r.y = __uint_as_float(v & 0xffff0000u);
    return r;
}

typedef __attribute__((ext_vector_type(8))) short bf16x8;
typedef __attribute__((ext_vector_type(4))) float f32x4;

// ---------------- W1 -> bf16 B-fragment-order buffer (one-time prep) ----------------
__global__ __launch_bounds__(256) void wprep_kernel(const float* __restrict__ W1,
                                                    unsigned short* __restrict__ wfrag)
{
    int gid = blockIdx.x * 256 + threadIdx.x;
    if (gid >= KF * F1) return;
    int k = gid >> 7, nn = gid & 127;
    int kt = k >> 6, ks = (k >> 5) & 1, oct = (k >> 3) & 3, e = k & 7;
    int nt = nn >> 4, ln = (nn & 15) + 16 * oct;
    int idx = (((kt * 8 + nt) * 2 + ks) * 64 + ln) * 8 + e;
    wfrag[idx] = (unsigned short)bf16r(W1[gid]);
}

// ---------------- FAT KERNEL: gemm1 (MFMA, blocks < G_gemm) || histrank (rest) ----------------
// The two halves are data-independent: gemm1 reads x/wfrag, histrank reads ei.
// Both are latency-bound with idle pipes -> co-residency overlaps them.
__global__ __launch_bounds__(256) void gemm1_hist_kernel(const float* __restrict__ x,
        const unsigned short* __restrict__ wfrag,
        const float* __restrict__ att_src, const float* __restrict__ att_dst,
        unsigned short* __restrict__ h1u, float* __restrict__ a_src, float* __restrict__ a_dst,
        int n, int G_gemm,
        const int* __restrict__ ei, int E, int Etot,
        int* __restrict__ counts, int* __restrict__ rank)
{
    __shared__ __align__(16) unsigned short Al[4096];  // A 64x64 frag-order, 8KB
    __shared__ __align__(16) unsigned short Bl[8192];  // B 64x128 frag-order, 16KB
    const int t = threadIdx.x;

    if ((int)blockIdx.x >= G_gemm) {
        // ---- histrank block: counts histogram + per-edge rank, 8 edges/thread ----
        const int base = ((int)blockIdx.x - G_gemm) * 2048 + t;
#pragma unroll
        for (int q = 0; q < 8; ++q) {
            int i = base + q * 256;
            if (i < Etot) {
                int dst = (i < E) ? ei[E + i] : (i - E);
                rank[i] = atomicAdd(&counts[dst], 1);
            }
        }
        return;
    }

    // ---- gemm1 block (round-8/10 measured-best form) ----
    const int w = t >> 6, lane = t & 63;
    const int row0 = blockIdx.x * BM;

    f32x4 acc[8];
#pragma unroll
    for (int i = 0; i < 8; ++i) acc[i] = (f32x4){0.f, 0.f, 0.f, 0.f};

    for (int kt = 0; kt < 4; ++kt) {
        // stage A: x[row0..+64][kt*64..+64] -> bf16 fragment order
        {
            const int k4 = t & 15;
            const int ks = k4 >> 3;
            const int oct = (k4 >> 1) & 3;
            const int koff = (k4 & 1) * 4;
#pragma unroll
            for (int it = 0; it < 4; ++it) {
                int r = (t >> 4) + it * 16;
                int gr = row0 + r;
                float4 v = make_float4(0.f, 0.f, 0.f, 0.f);
                if (gr < n) v = *(const float4*)&x[(size_t)gr * KF + kt * 64 + k4 * 4];
                int ln = (r & 15) + 16 * oct;
                int rt = r >> 4;
                int idx = ((rt * 2 + ks) * 64 + ln) * 8 + koff;
                uint2 p;
                p.x = bf16pack2(v.x, v.y);
                p.y = bf16pack2(v.z, v.w);
                *(uint2*)&Al[idx] = p;
            }
        }
        // stage B: linear 16KB copy of precomputed fragment-order tile
        {
            const uint4* src = (const uint4*)wfrag + kt * 1024;
            uint4* dstp = (uint4*)Bl;
#pragma unroll
            for (int i = 0; i < 4; ++i) dstp[t + i * 256] = src[t + i * 256];
        }
        __syncthreads();
        bf16x8 a0 = *(const bf16x8*)&Al[(w * 2 + 0) * 512 + lane * 8];
        bf16x8 a1 = *(const bf16x8*)&Al[(w * 2 + 1) * 512 + lane * 8];
#pragma unroll
        for (int nt = 0; nt < 8; ++nt) {
            bf16x8 b0 = *(const bf16x8*)&Bl[(nt * 2 + 0) * 512 + lane * 8];
            bf16x8 b1 = *(const bf16x8*)&Bl[(nt * 2 + 1) * 512 + lane * 8];
            acc[nt] = __builtin_amdgcn_mfma_f32_16x16x32_bf16(a0, b0, acc[nt], 0, 0, 0);
            acc[nt] = __builtin_amdgcn_mfma_f32_16x16x32_bf16(a1, b1, acc[nt], 0, 0, 0);
        }
        __syncthreads();
    }

    // epilogue: C layout col=lane&15, row=(lane>>4)*4+reg  [m89-verified]
    const int col = lane & 15, g = lane >> 4;
    const int rbase = row0 + w * 16 + g * 4;
#pragma unroll
    for (int nt = 0; nt < 8; ++nt) {
        float asv = att_src[nt * 16 + col];
        float adv = att_dst[nt * 16 + col];
#pragma unroll
        for (int reg = 0; reg < 4; ++reg) {
            int row = rbase + reg;
            float hv = acc[nt][reg];
            if (row < n) h1u[(size_t)row * F1 + nt * 16 + col] = (unsigned short)bf16r(hv);
            float ps = hv * asv, pd = hv * adv;
            ps += __shfl_xor(ps, 1); ps += __shfl_xor(ps, 2);
            ps += __shfl_xor(ps, 4); ps += __shfl_xor(ps, 8);
            pd += __shfl_xor(pd, 1); pd += __shfl_xor(pd, 2);
            pd += __shfl_xor(pd, 4); pd += __shfl_xor(pd, 8);
            if (col == 0 && row < n) {
                a_src[row * NH + nt] = ps;
                a_dst[row * NH + nt] = pd;
            }
        }
    }
}

// ---------------- CSR scans + fill ----------------
__global__ __launch_bounds__(256) void scan1_kernel(const int* __restrict__ counts,
                                                    int* __restrict__ bsum, int n)
{
    __shared__ int lds[256];
    const int t = threadIdx.x;
    const int base = blockIdx.x * 1024 + t * 4;
    int s = 0;
#pragma unroll
    for (int q = 0; q < 4; ++q) { int i = base + q; if (i < n) s += counts[i]; }
    lds[t] = s;
    __syncthreads();
#pragma unroll
    for (int off = 128; off > 0; off >>= 1) {
        if (t < off) lds[t] += lds[t + off];
        __syncthreads();
    }
    if (t == 0) bsum[blockIdx.x] = lds[0];
}

__global__ __launch_bounds__(256) void scan2_kernel(const int* __restrict__ bsum,
                                                    int* __restrict__ boffs, int nb,
                                                    int* __restrict__ indptr, int n, int Etot)
{
    __shared__ int lds[256];
    const int t = threadIdx.x;
    lds[t] = (t < nb) ? bsum[t] : 0;
    __syncthreads();
    for (int off = 1; off < 256; off <<= 1) {
        int v = (t >= off) ? lds[t - off] : 0;
        __syncthreads();
        lds[t] += v;
        __syncthreads();
    }
    if (t < nb) boffs[t] = (t == 0) ? 0 : lds[t - 1];
    if (t == 0) indptr[n] = Etot;
}

__global__ __launch_bounds__(256) void scan3_kernel(const int* __restrict__ counts,
                                                    const int* __restrict__ boffs,
                                                    int* __restrict__ indptr, int n)
{
    __shared__ int lds[256];
    const int t = threadIdx.x;
    const int base = blockIdx.x * 1024 + t * 4;
    int c[4];
    int s = 0;
#pragma unroll
    for (int q = 0; q < 4; ++q) {
        int i = base + q;
        c[q] = (i < n) ? counts[i] : 0;
        s += c[q];
    }
    lds[t] = s;
    __syncthreads();
    for (int off = 1; off < 256; off <<= 1) {
        int v = (t >= off) ? lds[t - off] : 0;
        __syncthreads();
        lds[t] += v;
        __syncthreads();
    }
    int run = boffs[blockIdx.x] + lds[t] - s;
#pragma unroll
    for (int q = 0; q < 4; ++q) {
        int i = base + q;
        if (i < n) indptr[i] = run;
        run += c[q];
    }
}

__global__ __launch_bounds__(256) void fill_kernel(const int* __restrict__ ei, int E, int Etot,
                                                   const int* __restrict__ indptr,
                                                   const int* __restrict__ rank,
                                                   int* __restrict__ sorted_src)
{
    const int base = blockIdx.x * 2048 + threadIdx.x;
#pragma unroll
    for (int q = 0; q < 8; ++q) {
        int i = base + q * 256;
        if (i < Etot) {
            int src, dst;
            if (i < E) { src = ei[i]; dst = ei[E + i]; }
            else       { src = i - E; dst = i - E; }
            sorted_src[indptr[dst] + rank[i]] = src;
        }
    }
}

// ---------------- layer-1 aggregation: wave/dst, bf16 gathers, 4-way unroll ----------------
__global__ __launch_bounds__(256) void agg1_kernel(const unsigned* __restrict__ h1b,
        const float* __restrict__ a_src, const float* __restrict__ a_dst,
        const int* __restrict__ indptr, const int* __restrict__ ssrc,
        const float* __restrict__ b1, unsigned* __restrict__ out1b, int n)
{
    const int wave = threadIdx.x >> 6, lane = threadIdx.x & 63;
    const int dst = blockIdx.x * 4 + wave;
    if (dst >= n) return;
    const int h = lane >> 3;              // head (2 channels/lane, 8 lanes/head)
    const float ad = a_dst[dst * NH + h];
    const int beg = indptr[dst], end = indptr[dst + 1];
    float s0 = 0.f, s1 = 0.f, s2 = 0.f, s3 = 0.f;
    float ax0 = 0.f, ay0 = 0.f, ax1 = 0.f, ay1 = 0.f;
    float ax2 = 0.f, ay2 = 0.f, ax3 = 0.f, ay3 = 0.f;
    int j = beg;
    for (; j + 4 <= end; j += 4) {
        int sc0 = ssrc[j], sc1 = ssrc[j + 1], sc2 = ssrc[j + 2], sc3 = ssrc[j + 3];
        float as0 = a_src[sc0 * NH + h];
        float as1 = a_src[sc1 * NH + h];
        float as2 = a_src[sc2 * NH + h];
        float as3 = a_src[sc3 * NH + h];
        unsigned v0 = h1b[(size_t)sc0 * 64 + lane];
        unsigned v1 = h1b[(size_t)sc1 * 64 + lane];
        unsigned v2 = h1b[(size_t)sc2 * 64 + lane];
        unsigned v3 = h1b[(size_t)sc3 * 64 + lane];
        float p0 = __expf(lrelu(as0 + ad));
        float p1 = __expf(lrelu(as1 + ad));
        float p2 = __expf(lrelu(as2 + ad));
        float p3 = __expf(lrelu(as3 + ad));
        float2 hv0 = bf2unpack(v0), hv1 = bf2unpack(v1);
        float2 hv2 = bf2unpack(v2), hv3 = bf2unpack(v3);
        s0 += p0; ax0 += p0 * hv0.x; ay0 += p0 * hv0.y;
        s1 += p1; ax1 += p1 * hv1.x; ay1 += p1 * hv1.y;
        s2 += p2; ax2 += p2 * hv2.x; ay2 += p2 * hv2.y;
        s3 += p3; ax3 += p3 * hv3.x; ay3 += p3 * hv3.y;
    }
    for (; j < end; ++j) {
        int sc = ssrc[j];
        float as = a_src[sc * NH + h];
        float2 hv = bf2unpack(h1b[(size_t)sc * 64 + lane]);
        float p = __expf(lrelu(as + ad));
        s0 += p; ax0 += p * hv.x; ay0 += p * hv.y;
    }
    float s = (s0 + s1) + (s2 + s3);
    float accx = (ax0 + ax1) + (ax2 + ax3);
    float accy = (ay0 + ay1) + (ay2 + ay3);
    float inv = 1.f / (s + 1e-16f);
    float2 bb = *(const float2*)&b1[lane * 2];
    float ox = fmaxf(accx * inv + bb.x, 0.f);   // fused ReLU
    float oy = fmaxf(accy * inv + bb.y, 0.f);
    out1b[(size_t)dst * 64 + lane] = bf16pack2(ox, oy);
}

// ---------------- GEMM2 + layer-2 attention logits (bf16 in, bf16 h2 out) ----------------
__global__ __launch_bounds__(256) void gemm2_kernel(const unsigned* __restrict__ out1b,
        const float* __restrict__ W2, const float* __restrict__ atts2,
        const float* __restrict__ attd2,
        unsigned short* __restrict__ h2us, float* __restrict__ a_src, float* __restrict__ a_dst, int n)
{
    __shared__ float wl[128][NCLS];    // 20,480B
    __shared__ float xs[64][68];       // 17,408B
    const int t = threadIdx.x;
    const int row0 = blockIdx.x * 64;
    const int rg = t >> 3;            // rows 2rg, 2rg+1
    const int cg = t & 7;             // cols 5cg..5cg+4
    const int r0 = rg * 2;

#pragma unroll
    for (int i = t; i < 1280; i += 256)
        *(float4*)&wl[0][0 + i * 4] = *(const float4*)&W2[i * 4];

    float acc[2][5];
#pragma unroll
    for (int i = 0; i < 2; ++i)
#pragma unroll
        for (int j = 0; j < 5; ++j) acc[i][j] = 0.f;

    for (int kh = 0; kh < 2; ++kh) {
        // stage x half-tile from bf16: 64 rows x 16 uint2 (4 channels each)
#pragma unroll
        for (int i = t; i < 1024; i += 256) {
            int r = i >> 4, u2 = i & 15;
            int gr = row0 + r;
            float4 v = make_float4(0.f, 0.f, 0.f, 0.f);
            if (gr < n) {
                uint2 pk = *(const uint2*)&out1b[(size_t)gr * 64 + kh * 32 + u2 * 2];
                float2 ab = bf2unpack(pk.x);
                float2 cd = bf2unpack(pk.y);
                v = make_float4(ab.x, ab.y, cd.x, cd.y);
            }
            *(float4*)&xs[r][u2 * 4] = v;
        }
        __syncthreads();
#pragma unroll 4
        for (int k = 0; k < 64; ++k) {
            float xa = xs[r0][k];
            float xb = xs[r0 + 1][k];
            const float* wr = &wl[kh * 64 + k][cg * 5];
#pragma unroll
            for (int j = 0; j < 5; ++j) {
                float w = wr[j];
                acc[0][j] += xa * w;
                acc[1][j] += xb * w;
            }
        }
        __syncthreads();
    }

    float as5[5], ad5[5];
#pragma unroll
    for (int j = 0; j < 5; ++j) {
        as5[j] = atts2[cg * 5 + j];
        ad5[j] = attd2[cg * 5 + j];
    }
#pragma unroll
    for (int i = 0; i < 2; ++i) {
        int row = row0 + r0 + i;
        if (row >= n) break;
#pragma unroll
        for (int j = 0; j < 5; ++j)
            h2us[(size_t)row * NCLS + cg * 5 + j] = (unsigned short)bf16r(acc[i][j]);
        float ps = acc[i][0] * as5[0] + acc[i][1] * as5[1] + acc[i][2] * as5[2]
                 + acc[i][3] * as5[3] + acc[i][4] * as5[4];
        float pd = acc[i][0] * ad5[0] + acc[i][1] * ad5[1] + acc[i][2] * ad5[2]
                 + acc[i][3] * ad5[3] + acc[i][4] * ad5[4];
        ps += __shfl_xor(ps, 1); ps += __shfl_xor(ps, 2); ps += __shfl_xor(ps, 4);
        pd += __shfl_xor(pd, 1); pd += __shfl_xor(pd, 2); pd += __shfl_xor(pd, 4);
        if (cg == 0) { a_src[row] = ps; a_dst[row] = pd; }
    }
}

// ---------------- layer-2 aggregation: 3 dsts/wave, bf16 gathers, 4-way unroll ----------------
__global__ __launch_bounds__(256) void agg2_kernel(const unsigned* __restrict__ h2b,
        const float* __restrict__ a_src, const float* __restrict__ a_dst,
        const int* __restrict__ indptr, const int* __restrict__ ssrc,
        const float* __restrict__ b2, float* __restrict__ out, int n)
{
    const int wave = threadIdx.x >> 6, lane = threadIdx.x & 63;
    const int grp = lane / 20;            // 0..2 (lanes 60..63 idle)
    const int sub = lane - grp * 20;      // classes sub*2, sub*2+1
    const int dst = blockIdx.x * 12 + wave * 3 + grp;
    const bool valid = (grp < 3) && (dst < n);
    const float ad = valid ? a_dst[dst] : 0.f;
    int beg = 0, end = 0;
    if (valid) { beg = indptr[dst]; end = indptr[dst + 1]; }
    float s0 = 0.f, s1 = 0.f, s2 = 0.f, s3 = 0.f;
    float ax0 = 0.f, ay0 = 0.f, ax1 = 0.f, ay1 = 0.f;
    float ax2 = 0.f, ay2 = 0.f, ax3 = 0.f, ay3 = 0.f;
    int j = beg;
    for (; j + 4 <= end; j += 4) {
        int sc0 = ssrc[j], sc1 = ssrc[j + 1], sc2 = ssrc[j + 2], sc3 = ssrc[j + 3];
        float p0 = __expf(lrelu(a_src[sc0] + ad));
        float p1 = __expf(lrelu(a_src[sc1] + ad));
        float p2 = __expf(lrelu(a_src[sc2] + ad));
        float p3 = __expf(lrelu(a_src[sc3] + ad));
        float2 h0 = bf2unpack(h2b[(size_t)sc0 * 20 + sub]);
        float2 h1v = bf2unpack(h2b[(size_t)sc1 * 20 + sub]);
        float2 h2v = bf2unpack(h2b[(size_t)sc2 * 20 + sub]);
        float2 h3v = bf2unpack(h2b[(size_t)sc3 * 20 + sub]);
        s0 += p0; ax0 += p0 * h0.x;  ay0 += p0 * h0.y;
        s1 += p1; ax1 += p1 * h1v.x; ay1 += p1 * h1v.y;
        s2 += p2; ax2 += p2 * h2v.x; ay2 += p2 * h2v.y;
        s3 += p3; ax3 += p3 * h3v.x; ay3 += p3 * h3v.y;
    }
    for (; j < end; ++j) {
        int sc = ssrc[j];
        float p = __expf(lrelu(a_src[sc] + ad));
        float2 hv = bf2unpack(h2b[(size_t)sc * 20 + sub]);
        s0 += p; ax0 += p * hv.x; ay0 += p * hv.y;
    }
    if (valid) {
        float s = (s0 + s1) + (s2 + s3);
        float accx = (ax0 + ax1) + (ax2 + ax3);
        float accy = (ay0 + ay1) + (ay2 + ay3);
        float inv = 1.f / (s + 1e-16f);
        float2 o;
        o.x = accx * inv + b2[sub * 2];
        o.y = accy * inv + b2[sub * 2 + 1];
        *(float2*)&out[(size_t)dst * NCLS + sub * 2] = o;
    }
}

extern "C" void kernel_launch(void* const* d_in, const int* in_sizes, int n_in,
                              void* d_out, int out_size, void* d_ws, size_t ws_size,
                              hipStream_t stream)
{
    const float* x   = (const float*)d_in[0];
    const int*   ei  = (const int*)d_in[1];   // edge_index, int32 per harness contract
    const float* W1  = (const float*)d_in[2];
    const float* as1 = (const float*)d_in[3];
    const float* ad1 = (const float*)d_in[4];
    const float* b1  = (const float*)d_in[5];
    const float* W2  = (const float*)d_in[6];
    const float* as2 = (const float*)d_in[7];
    const float* ad2 = (const float*)d_in[8];
    const float* b2  = (const float*)d_in[9];
    float* out = (float*)d_out;

    const int n    = in_sizes[0] / KF;   // 100000
    const int E    = in_sizes[1] / 2;    // 1600000
    const int Etot = E + n;              // + self loops

    // workspace layout (16B aligned)
    char* ws = (char*)d_ws;
    unsigned* h1b   = (unsigned*)ws;                   // 25.6 MB  [n,64] bf16x2
    unsigned* out1b = (unsigned*)(ws + 25600000);      // 25.6 MB  [n,64] bf16x2
    float* a_s1     = (float*)(ws + 51200000);         // 3.2 MB   [n,8]
    float* a_d1     = (float*)(ws + 54400000);         // 3.2 MB   [n,8]
    int*   indptr   = (int*)  (ws + 57600000);         // [n+1]
    int*   counts   = (int*)  (ws + 58000016);         // [n]
    int*   ssrc     = (int*)  (ws + 58400016);         // 6.8 MB   [Etot]
    unsigned short* wfrag = (unsigned short*)(ws + 65200016);  // 64 KB W1 frag-order bf16
    int*   rank     = (int*)  (ws + 65270016);         // 6.8 MB   [Etot]
    int*   bsum     = (int*)  (ws + 72070016);
    int*   boffs    = (int*)  (ws + 72074112);
    // layer-2 buffers alias h1b region (h1b dead after agg1; gemm2 runs after agg1)
    unsigned* h2b   = (unsigned*)ws;                   // 8 MB     [n,20] bf16x2
    float* a_s2     = (float*)(ws + 8000000);          // 400 KB
    float* a_d2     = (float*)(ws + 8400000);          // 400 KB

    const int nb = (n + 1023) / 1024;    // 98 scan chunks (<= 256)
    const int G_gemm = (n + BM - 1) / BM;          // 1563 gemm1 blocks
    const int G_hist = (Etot + 2047) / 2048;       // 831 histrank blocks
    dim3 b256(256);

    hipMemsetAsync(counts, 0, n * sizeof(int), stream);
    wprep_kernel<<<dim3((KF * F1 + 255) / 256), b256, 0, stream>>>(W1, wfrag);
    gemm1_hist_kernel<<<dim3(G_gemm + G_hist), b256, 0, stream>>>(
        x, wfrag, as1, ad1, (unsigned short*)h1b, a_s1, a_d1, n, G_gemm,
        ei, E, Etot, counts, rank);
    scan1_kernel<<<dim3(nb), b256, 0, stream>>>(counts, bsum, n);
    scan2_kernel<<<dim3(1), b256, 0, stream>>>(bsum, boffs, nb, indptr, n, Etot);
    scan3_kernel<<<dim3(nb), b256, 0, stream>>>(counts, boffs, indptr, n);
    fill_kernel<<<dim3((Etot + 2047) / 2048), b256, 0, stream>>>(ei, E, Etot, indptr, rank, ssrc);
    agg1_kernel<<<dim3((n + 3) / 4), b256, 0, stream>>>(h1b, a_s1, a_d1, indptr, ssrc, b1, out1b, n);
    gemm2_kernel<<<dim3((n + 63) / 64), b256, 0, stream>>>(out1b, W2, as2, ad2,
                                                           (unsigned short*)h2b, a_s2, a_d2, n);
    agg2_kernel<<<dim3((n + 11) / 12), b256, 0, stream>>>(h2b, a_s2, a_d2, indptr, ssrc, b2, out, n);
}

// Round 17
// 288.602 us; speedup vs baseline: 1.3857x; 1.1134x over previous
//
#include <hip/hip_runtime.h>
#include <math.h>

#define KF 256      // input features
#define F1 128      // layer-1 hidden (8 heads x 16)
#define NH 8        // heads layer 1
#define NC 16       // channels per head layer 1
#define NCLS 40     // layer-2 output classes
#define NEG 0.2f    // leaky relu slope
#define BM 64       // gemm1 row tile

static __device__ __forceinline__ float lrelu(float v) { return fmaxf(v, NEG * v); }

// round-to-nearest-even bf16 packing helpers
static __device__ __forceinline__ unsigned bf16r(float a) {
    unsigned u = __float_as_uint(a);
    return (u + 0x7fffu + ((u >> 16) & 1u)) >> 16;
}
static __device__ __forceinline__ unsigned bf16pack2(float a, float b) {
    return bf16r(a) | (bf16r(b) << 16);
}
static __device__ __forceinline__ float2 bf2unpack(unsigned v) {
    float2 r;
    r.x = __uint_as_float(v << 16);
    r.y = __uint_as_float(v & 0xffff0000u);
    return r;
}

typedef __attribute__((ext_vector_type(8))) short bf16x8;
typedef __attribute__((ext_vector_type(4))) float f32x4;

// ---------------- W1 -> bf16 B-fragment-order buffer (one-time prep) ----------------
__global__ __launch_bounds__(256) void wprep_kernel(const float* __restrict__ W1,
                                                    unsigned short* __restrict__ wfrag)
{
    int gid = blockIdx.x * 256 + threadIdx.x;
    if (gid >= KF * F1) return;
    int k = gid >> 7, nn = gid & 127;
    int kt = k >> 6, ks = (k >> 5) & 1, oct = (k >> 3) & 3, e = k & 7;
    int nt = nn >> 4, ln = (nn & 15) + 16 * oct;
    int idx = (((kt * 8 + nt) * 2 + ks) * 64 + ln) * 8 + e;
    wfrag[idx] = (unsigned short)bf16r(W1[gid]);
}

// ---------------- FAT KERNEL: gemm1 (MFMA) || histrank, INTERLEAVED in blockIdx ----------------
// hist blocks striped evenly among gemm blocks so both populations dispatch from t=0:
// c = b*G_hist/T; is_hist iff (b+1)*G_hist/T > c. (T*G_hist ~ 2M, fits u32.)
__global__ __launch_bounds__(256) void gemm1_hist_kernel(const float* __restrict__ x,
        const unsigned short* __restrict__ wfrag,
        const float* __restrict__ att_src, const float* __restrict__ att_dst,
        unsigned short* __restrict__ h1u, float* __restrict__ a_src, float* __restrict__ a_dst,
        int n, int T, int G_hist,
        const int* __restrict__ ei, int E, int Etot,
        int* __restrict__ counts, int* __restrict__ rank)
{
    __shared__ __align__(16) unsigned short Al[4096];  // A 64x64 frag-order, 8KB
    __shared__ __align__(16) unsigned short Bl[8192];  // B 64x128 frag-order, 16KB
    const int t = threadIdx.x;

    const unsigned b = blockIdx.x;
    const unsigned c = (b * (unsigned)G_hist) / (unsigned)T;
    const bool is_hist = ((b + 1u) * (unsigned)G_hist) / (unsigned)T > c;

    if (is_hist) {
        // ---- histrank block c: counts histogram + per-edge rank, 8 edges/thread ----
        const int base = (int)c * 2048 + t;
#pragma unroll
        for (int q = 0; q < 8; ++q) {
            int i = base + q * 256;
            if (i < Etot) {
                int dst = (i < E) ? ei[E + i] : (i - E);
                rank[i] = atomicAdd(&counts[dst], 1);
            }
        }
        return;
    }

    // ---- gemm1 block (round-8/10 measured-best form) ----
    const int gblk = (int)(b - c);
    const int w = t >> 6, lane = t & 63;
    const int row0 = gblk * BM;

    f32x4 acc[8];
#pragma unroll
    for (int i = 0; i < 8; ++i) acc[i] = (f32x4){0.f, 0.f, 0.f, 0.f};

    for (int kt = 0; kt < 4; ++kt) {
        // stage A: x[row0..+64][kt*64..+64] -> bf16 fragment order
        {
            const int k4 = t & 15;
            const int ks = k4 >> 3;
            const int oct = (k4 >> 1) & 3;
            const int koff = (k4 & 1) * 4;
#pragma unroll
            for (int it = 0; it < 4; ++it) {
                int r = (t >> 4) + it * 16;
                int gr = row0 + r;
                float4 v = make_float4(0.f, 0.f, 0.f, 0.f);
                if (gr < n) v = *(const float4*)&x[(size_t)gr * KF + kt * 64 + k4 * 4];
                int ln = (r & 15) + 16 * oct;
                int rt = r >> 4;
                int idx = ((rt * 2 + ks) * 64 + ln) * 8 + koff;
                uint2 p;
                p.x = bf16pack2(v.x, v.y);
                p.y = bf16pack2(v.z, v.w);
                *(uint2*)&Al[idx] = p;
            }
        }
        // stage B: linear 16KB copy of precomputed fragment-order tile
        {
            const uint4* src = (const uint4*)wfrag + kt * 1024;
            uint4* dstp = (uint4*)Bl;
#pragma unroll
            for (int i = 0; i < 4; ++i) dstp[t + i * 256] = src[t + i * 256];
        }
        __syncthreads();
        bf16x8 a0 = *(const bf16x8*)&Al[(w * 2 + 0) * 512 + lane * 8];
        bf16x8 a1 = *(const bf16x8*)&Al[(w * 2 + 1) * 512 + lane * 8];
#pragma unroll
        for (int nt = 0; nt < 8; ++nt) {
            bf16x8 b0 = *(const bf16x8*)&Bl[(nt * 2 + 0) * 512 + lane * 8];
            bf16x8 b1 = *(const bf16x8*)&Bl[(nt * 2 + 1) * 512 + lane * 8];
            acc[nt] = __builtin_amdgcn_mfma_f32_16x16x32_bf16(a0, b0, acc[nt], 0, 0, 0);
            acc[nt] = __builtin_amdgcn_mfma_f32_16x16x32_bf16(a1, b1, acc[nt], 0, 0, 0);
        }
        __syncthreads();
    }

    // epilogue: C layout col=lane&15, row=(lane>>4)*4+reg  [m89-verified]
    const int col = lane & 15, g = lane >> 4;
    const int rbase = row0 + w * 16 + g * 4;
#pragma unroll
    for (int nt = 0; nt < 8; ++nt) {
        float asv = att_src[nt * 16 + col];
        float adv = att_dst[nt * 16 + col];
#pragma unroll
        for (int reg = 0; reg < 4; ++reg) {
            int row = rbase + reg;
            float hv = acc[nt][reg];
            if (row < n) h1u[(size_t)row * F1 + nt * 16 + col] = (unsigned short)bf16r(hv);
            float ps = hv * asv, pd = hv * adv;
            ps += __shfl_xor(ps, 1); ps += __shfl_xor(ps, 2);
            ps += __shfl_xor(ps, 4); ps += __shfl_xor(ps, 8);
            pd += __shfl_xor(pd, 1); pd += __shfl_xor(pd, 2);
            pd += __shfl_xor(pd, 4); pd += __shfl_xor(pd, 8);
            if (col == 0 && row < n) {
                a_src[row * NH + nt] = ps;
                a_dst[row * NH + nt] = pd;
            }
        }
    }
}

// ---------------- CSR scans + fill ----------------
__global__ __launch_bounds__(256) void scan1_kernel(const int* __restrict__ counts,
                                                    int* __restrict__ bsum, int n)
{
    __shared__ int lds[256];
    const int t = threadIdx.x;
    const int base = blockIdx.x * 1024 + t * 4;
    int s = 0;
#pragma unroll
    for (int q = 0; q < 4; ++q) { int i = base + q; if (i < n) s += counts[i]; }
    lds[t] = s;
    __syncthreads();
#pragma unroll
    for (int off = 128; off > 0; off >>= 1) {
        if (t < off) lds[t] += lds[t + off];
        __syncthreads();
    }
    if (t == 0) bsum[blockIdx.x] = lds[0];
}

__global__ __launch_bounds__(256) void scan2_kernel(const int* __restrict__ bsum,
                                                    int* __restrict__ boffs, int nb,
                                                    int* __restrict__ indptr, int n, int Etot)
{
    __shared__ int lds[256];
    const int t = threadIdx.x;
    lds[t] = (t < nb) ? bsum[t] : 0;
    __syncthreads();
    for (int off = 1; off < 256; off <<= 1) {
        int v = (t >= off) ? lds[t - off] : 0;
        __syncthreads();
        lds[t] += v;
        __syncthreads();
    }
    if (t < nb) boffs[t] = (t == 0) ? 0 : lds[t - 1];
    if (t == 0) indptr[n] = Etot;
}

__global__ __launch_bounds__(256) void scan3_kernel(const int* __restrict__ counts,
                                                    const int* __restrict__ boffs,
                                                    int* __restrict__ indptr, int n)
{
    __shared__ int lds[256];
    const int t = threadIdx.x;
    const int base = blockIdx.x * 1024 + t * 4;
    int c[4];
    int s = 0;
#pragma unroll
    for (int q = 0; q < 4; ++q) {
        int i = base + q;
        c[q] = (i < n) ? counts[i] : 0;
        s += c[q];
    }
    lds[t] = s;
    __syncthreads();
    for (int off = 1; off < 256; off <<= 1) {
        int v = (t >= off) ? lds[t - off] : 0;
        __syncthreads();
        lds[t] += v;
        __syncthreads();
    }
    int run = boffs[blockIdx.x] + lds[t] - s;
#pragma unroll
    for (int q = 0; q < 4; ++q) {
        int i = base + q;
        if (i < n) indptr[i] = run;
        run += c[q];
    }
}

__global__ __launch_bounds__(256) void fill_kernel(const int* __restrict__ ei, int E, int Etot,
                                                   const int* __restrict__ indptr,
                                                   const int* __restrict__ rank,
                                                   int* __restrict__ sorted_src)
{
    const int base = blockIdx.x * 2048 + threadIdx.x;
#pragma unroll
    for (int q = 0; q < 8; ++q) {
        int i = base + q * 256;
        if (i < Etot) {
            int src, dst;
            if (i < E) { src = ei[i]; dst = ei[E + i]; }
            else       { src = i - E; dst = i - E; }
            sorted_src[indptr[dst] + rank[i]] = src;
        }
    }
}

// ---------------- layer-1 aggregation: wave/dst, bf16 gathers, 4-way unroll ----------------
__global__ __launch_bounds__(256) void agg1_kernel(const unsigned* __restrict__ h1b,
        const float* __restrict__ a_src, const float* __restrict__ a_dst,
        const int* __restrict__ indptr, const int* __restrict__ ssrc,
        const float* __restrict__ b1, unsigned* __restrict__ out1b, int n)
{
    const int wave = threadIdx.x >> 6, lane = threadIdx.x & 63;
    const int dst = blockIdx.x * 4 + wave;
    if (dst >= n) return;
    const int h = lane >> 3;              // head (2 channels/lane, 8 lanes/head)
    const float ad = a_dst[dst * NH + h];
    const int beg = indptr[dst], end = indptr[dst + 1];
    float s0 = 0.f, s1 = 0.f, s2 = 0.f, s3 = 0.f;
    float ax0 = 0.f, ay0 = 0.f, ax1 = 0.f, ay1 = 0.f;
    float ax2 = 0.f, ay2 = 0.f, ax3 = 0.f, ay3 = 0.f;
    int j = beg;
    for (; j + 4 <= end; j += 4) {
        int sc0 = ssrc[j], sc1 = ssrc[j + 1], sc2 = ssrc[j + 2], sc3 = ssrc[j + 3];
        float as0 = a_src[sc0 * NH + h];
        float as1 = a_src[sc1 * NH + h];
        float as2 = a_src[sc2 * NH + h];
        float as3 = a_src[sc3 * NH + h];
        unsigned v0 = h1b[(size_t)sc0 * 64 + lane];
        unsigned v1 = h1b[(size_t)sc1 * 64 + lane];
        unsigned v2 = h1b[(size_t)sc2 * 64 + lane];
        unsigned v3 = h1b[(size_t)sc3 * 64 + lane];
        float p0 = __expf(lrelu(as0 + ad));
        float p1 = __expf(lrelu(as1 + ad));
        float p2 = __expf(lrelu(as2 + ad));
        float p3 = __expf(lrelu(as3 + ad));
        float2 hv0 = bf2unpack(v0), hv1 = bf2unpack(v1);
        float2 hv2 = bf2unpack(v2), hv3 = bf2unpack(v3);
        s0 += p0; ax0 += p0 * hv0.x; ay0 += p0 * hv0.y;
        s1 += p1; ax1 += p1 * hv1.x; ay1 += p1 * hv1.y;
        s2 += p2; ax2 += p2 * hv2.x; ay2 += p2 * hv2.y;
        s3 += p3; ax3 += p3 * hv3.x; ay3 += p3 * hv3.y;
    }
    for (; j < end; ++j) {
        int sc = ssrc[j];
        float as = a_src[sc * NH + h];
        float2 hv = bf2unpack(h1b[(size_t)sc * 64 + lane]);
        float p = __expf(lrelu(as + ad));
        s0 += p; ax0 += p * hv.x; ay0 += p * hv.y;
    }
    float s = (s0 + s1) + (s2 + s3);
    float accx = (ax0 + ax1) + (ax2 + ax3);
    float accy = (ay0 + ay1) + (ay2 + ay3);
    float inv = 1.f / (s + 1e-16f);
    float2 bb = *(const float2*)&b1[lane * 2];
    float ox = fmaxf(accx * inv + bb.x, 0.f);   // fused ReLU
    float oy = fmaxf(accy * inv + bb.y, 0.f);
    out1b[(size_t)dst * 64 + lane] = bf16pack2(ox, oy);
}

// ---------------- GEMM2 + layer-2 attention logits (bf16 in, bf16 h2 out) ----------------
__global__ __launch_bounds__(256) void gemm2_kernel(const unsigned* __restrict__ out1b,
        const float* __restrict__ W2, const float* __restrict__ atts2,
        const float* __restrict__ attd2,
        unsigned short* __restrict__ h2us, float* __restrict__ a_src, float* __restrict__ a_dst, int n)
{
    __shared__ float wl[128][NCLS];    // 20,480B
    __shared__ float xs[64][68];       // 17,408B
    const int t = threadIdx.x;
    const int row0 = blockIdx.x * 64;
    const int rg = t >> 3;            // rows 2rg, 2rg+1
    const int cg = t & 7;             // cols 5cg..5cg+4
    const int r0 = rg * 2;

#pragma unroll
    for (int i = t; i < 1280; i += 256)
        *(float4*)&wl[0][0 + i * 4] = *(const float4*)&W2[i * 4];

    float acc[2][5];
#pragma unroll
    for (int i = 0; i < 2; ++i)
#pragma unroll
        for (int j = 0; j < 5; ++j) acc[i][j] = 0.f;

    for (int kh = 0; kh < 2; ++kh) {
        // stage x half-tile from bf16: 64 rows x 16 uint2 (4 channels each)
#pragma unroll
        for (int i = t; i < 1024; i += 256) {
            int r = i >> 4, u2 = i & 15;
            int gr = row0 + r;
            float4 v = make_float4(0.f, 0.f, 0.f, 0.f);
            if (gr < n) {
                uint2 pk = *(const uint2*)&out1b[(size_t)gr * 64 + kh * 32 + u2 * 2];
                float2 ab = bf2unpack(pk.x);
                float2 cd = bf2unpack(pk.y);
                v = make_float4(ab.x, ab.y, cd.x, cd.y);
            }
            *(float4*)&xs[r][u2 * 4] = v;
        }
        __syncthreads();
#pragma unroll 4
        for (int k = 0; k < 64; ++k) {
            float xa = xs[r0][k];
            float xb = xs[r0 + 1][k];
            const float* wr = &wl[kh * 64 + k][cg * 5];
#pragma unroll
            for (int j = 0; j < 5; ++j) {
                float w = wr[j];
                acc[0][j] += xa * w;
                acc[1][j] += xb * w;
            }
        }
        __syncthreads();
    }

    float as5[5], ad5[5];
#pragma unroll
    for (int j = 0; j < 5; ++j) {
        as5[j] = atts2[cg * 5 + j];
        ad5[j] = attd2[cg * 5 + j];
    }
#pragma unroll
    for (int i = 0; i < 2; ++i) {
        int row = row0 + r0 + i;
        if (row >= n) break;
#pragma unroll
        for (int j = 0; j < 5; ++j)
            h2us[(size_t)row * NCLS + cg * 5 + j] = (unsigned short)bf16r(acc[i][j]);
        float ps = acc[i][0] * as5[0] + acc[i][1] * as5[1] + acc[i][2] * as5[2]
                 + acc[i][3] * as5[3] + acc[i][4] * as5[4];
        float pd = acc[i][0] * ad5[0] + acc[i][1] * ad5[1] + acc[i][2] * ad5[2]
                 + acc[i][3] * ad5[3] + acc[i][4] * ad5[4];
        ps += __shfl_xor(ps, 1); ps += __shfl_xor(ps, 2); ps += __shfl_xor(ps, 4);
        pd += __shfl_xor(pd, 1); pd += __shfl_xor(pd, 2); pd += __shfl_xor(pd, 4);
        if (cg == 0) { a_src[row] = ps; a_dst[row] = pd; }
    }
}

// ---------------- layer-2 aggregation: 3 dsts/wave, bf16 gathers, 4-way unroll ----------------
__global__ __launch_bounds__(256) void agg2_kernel(const unsigned* __restrict__ h2b,
        const float* __restrict__ a_src, const float* __restrict__ a_dst,
        const int* __restrict__ indptr, const int* __restrict__ ssrc,
        const float* __restrict__ b2, float* __restrict__ out, int n)
{
    const int wave = threadIdx.x >> 6, lane = threadIdx.x & 63;
    const int grp = lane / 20;            // 0..2 (lanes 60..63 idle)
    const int sub = lane - grp * 20;      // classes sub*2, sub*2+1
    const int dst = blockIdx.x * 12 + wave * 3 + grp;
    const bool valid = (grp < 3) && (dst < n);
    const float ad = valid ? a_dst[dst] : 0.f;
    int beg = 0, end = 0;
    if (valid) { beg = indptr[dst]; end = indptr[dst + 1]; }
    float s0 = 0.f, s1 = 0.f, s2 = 0.f, s3 = 0.f;
    float ax0 = 0.f, ay0 = 0.f, ax1 = 0.f, ay1 = 0.f;
    float ax2 = 0.f, ay2 = 0.f, ax3 = 0.f, ay3 = 0.f;
    int j = beg;
    for (; j + 4 <= end; j += 4) {
        int sc0 = ssrc[j], sc1 = ssrc[j + 1], sc2 = ssrc[j + 2], sc3 = ssrc[j + 3];
        float p0 = __expf(lrelu(a_src[sc0] + ad));
        float p1 = __expf(lrelu(a_src[sc1] + ad));
        float p2 = __expf(lrelu(a_src[sc2] + ad));
        float p3 = __expf(lrelu(a_src[sc3] + ad));
        float2 h0 = bf2unpack(h2b[(size_t)sc0 * 20 + sub]);
        float2 h1v = bf2unpack(h2b[(size_t)sc1 * 20 + sub]);
        float2 h2v = bf2unpack(h2b[(size_t)sc2 * 20 + sub]);
        float2 h3v = bf2unpack(h2b[(size_t)sc3 * 20 + sub]);
        s0 += p0; ax0 += p0 * h0.x;  ay0 += p0 * h0.y;
        s1 += p1; ax1 += p1 * h1v.x; ay1 += p1 * h1v.y;
        s2 += p2; ax2 += p2 * h2v.x; ay2 += p2 * h2v.y;
        s3 += p3; ax3 += p3 * h3v.x; ay3 += p3 * h3v.y;
    }
    for (; j < end; ++j) {
        int sc = ssrc[j];
        float p = __expf(lrelu(a_src[sc] + ad));
        float2 hv = bf2unpack(h2b[(size_t)sc * 20 + sub]);
        s0 += p; ax0 += p * hv.x; ay0 += p * hv.y;
    }
    if (valid) {
        float s = (s0 + s1) + (s2 + s3);
        float accx = (ax0 + ax1) + (ax2 + ax3);
        float accy = (ay0 + ay1) + (ay2 + ay3);
        float inv = 1.f / (s + 1e-16f);
        float2 o;
        o.x = accx * inv + b2[sub * 2];
        o.y = accy * inv + b2[sub * 2 + 1];
        *(float2*)&out[(size_t)dst * NCLS + sub * 2] = o;
    }
}

extern "C" void kernel_launch(void* const* d_in, const int* in_sizes, int n_in,
                              void* d_out, int out_size, void* d_ws, size_t ws_size,
                              hipStream_t stream)
{
    const float* x   = (const float*)d_in[0];
    const int*   ei  = (const int*)d_in[1];   // edge_index, int32 per harness contract
    const float* W1  = (const float*)d_in[2];
    const float* as1 = (const float*)d_in[3];
    const float* ad1 = (const float*)d_in[4];
    const float* b1  = (const float*)d_in[5];
    const float* W2  = (const float*)d_in[6];
    const float* as2 = (const float*)d_in[7];
    const float* ad2 = (const float*)d_in[8];
    const float* b2  = (const float*)d_in[9];
    float* out = (float*)d_out;

    const int n    = in_sizes[0] / KF;   // 100000
    const int E    = in_sizes[1] / 2;    // 1600000
    const int Etot = E + n;              // + self loops

    // workspace layout (16B aligned)
    char* ws = (char*)d_ws;
    unsigned* h1b   = (unsigned*)ws;                   // 25.6 MB  [n,64] bf16x2
    unsigned* out1b = (unsigned*)(ws + 25600000);      // 25.6 MB  [n,64] bf16x2
    float* a_s1     = (float*)(ws + 51200000);         // 3.2 MB   [n,8]
    float* a_d1     = (float*)(ws + 54400000);         // 3.2 MB   [n,8]
    int*   indptr   = (int*)  (ws + 57600000);         // [n+1]
    int*   counts   = (int*)  (ws + 58000016);         // [n]
    int*   ssrc     = (int*)  (ws + 58400016);         // 6.8 MB   [Etot]
    unsigned short* wfrag = (unsigned short*)(ws + 65200016);  // 64 KB W1 frag-order bf16
    int*   rank     = (int*)  (ws + 65270016);         // 6.8 MB   [Etot]
    int*   bsum     = (int*)  (ws + 72070016);
    int*   boffs    = (int*)  (ws + 72074112);
    // layer-2 buffers alias h1b region (h1b dead after agg1; gemm2 runs after agg1)
    unsigned* h2b   = (unsigned*)ws;                   // 8 MB     [n,20] bf16x2
    float* a_s2     = (float*)(ws + 8000000);          // 400 KB
    float* a_d2     = (float*)(ws + 8400000);          // 400 KB

    const int nb = (n + 1023) / 1024;    // 98 scan chunks (<= 256)
    const int G_gemm = (n + BM - 1) / BM;          // 1563 gemm1 blocks
    const int G_hist = (Etot + 2047) / 2048;       // 831 histrank blocks
    const int T = G_gemm + G_hist;                 // 2394 total (T*G_hist < 2^31)
    dim3 b256(256);

    hipMemsetAsync(counts, 0, n * sizeof(int), stream);
    wprep_kernel<<<dim3((KF * F1 + 255) / 256), b256, 0, stream>>>(W1, wfrag);
    gemm1_hist_kernel<<<dim3(T), b256, 0, stream>>>(
        x, wfrag, as1, ad1, (unsigned short*)h1b, a_s1, a_d1, n, T, G_hist,
        ei, E, Etot, counts, rank);
    scan1_kernel<<<dim3(nb), b256, 0, stream>>>(counts, bsum, n);
    scan2_kernel<<<dim3(1), b256, 0, stream>>>(bsum, boffs, nb, indptr, n, Etot);
    scan3_kernel<<<dim3(nb), b256, 0, stream>>>(counts, boffs, indptr, n);
    fill_kernel<<<dim3((Etot + 2047) / 2048), b256, 0, stream>>>(ei, E, Etot, indptr, rank, ssrc);
    agg1_kernel<<<dim3((n + 3) / 4), b256, 0, stream>>>(h1b, a_s1, a_d1, indptr, ssrc, b1, out1b, n);
    gemm2_kernel<<<dim3((n + 63) / 64), b256, 0, stream>>>(out1b, W2, as2, ad2,
                                                           (unsigned short*)h2b, a_s2, a_d2, n);
    agg2_kernel<<<dim3((n + 11) / 12), b256, 0, stream>>>(h2b, a_s2, a_d2, indptr, ssrc, b2, out, n);
}